// Round 3
// baseline (112.867 us; speedup 1.0000x reference)
//
#include <hip/hip_runtime.h>
#include <math.h>

#define BB 4
#define CC 248
#define TT 500
#define DD 64

typedef float f32x4 __attribute__((ext_vector_type(4)));

__global__ __launch_bounds__(256) void csa_kernel(
    const float* __restrict__ x,
    const float* __restrict__ wq, const float* __restrict__ bq,
    const float* __restrict__ wk, const float* __restrict__ bk,
    const float* __restrict__ wv, const float* __restrict__ bv,
    float* __restrict__ out, float* __restrict__ wts)
{
    const int bt = blockIdx.x;          // 0 .. B*T-1
    const int b  = bt / TT;
    const int t  = bt % TT;
    const int tid  = threadIdx.x;
    const int wave = tid >> 6;
    const int lane = tid & 63;
    const int q    = lane & 31;         // index within half-wave
    const int h    = lane >> 5;         // which half-wave

    __shared__ __align__(16) float xs[CC];
    __shared__ __align__(16) float sRow[CC][4];   // {scl2, -m2, inv, 0} per row
    __shared__ float sred[8];
    __shared__ float sA, sB2, sXmax, sXmin, sYbar;

    // ---- load x slice: x[b, c, t] ----
    if (tid < CC) xs[tid] = x[((size_t)b * CC + tid) * TT + t];

    // ---- wave 1: a = wq.wk/8, b2 = bq.wk/8 ----
    if (wave == 1) {
        float wkv = wk[lane];
        float pa = wq[lane] * wkv;
        float pb = bq[lane] * wkv;
        #pragma unroll
        for (int off = 32; off > 0; off >>= 1) {
            pa += __shfl_xor(pa, off, 64);
            pb += __shfl_xor(pb, off, 64);
        }
        if (lane == 0) { sA = pa * 0.125f; sB2 = pb * 0.125f; }
    }
    __syncthreads();

    // ---- block reduce xmax / xmin ----
    float vmax = -INFINITY, vmin = INFINITY;
    if (tid < CC) { vmax = xs[tid]; vmin = vmax; }
    #pragma unroll
    for (int off = 32; off > 0; off >>= 1) {
        vmax = fmaxf(vmax, __shfl_xor(vmax, off, 64));
        vmin = fminf(vmin, __shfl_xor(vmin, off, 64));
    }
    if (lane == 0) { sred[wave] = vmax; sred[4 + wave] = vmin; }
    __syncthreads();
    if (tid == 0) {
        sXmax = fmaxf(fmaxf(sred[0], sred[1]), fmaxf(sred[2], sred[3]));
        sXmin = fminf(fminf(sred[4], sred[5]), fminf(sred[6], sred[7]));
    }
    __syncthreads();

    const float LOG2E = 1.4426950408889634f;
    const float a2   = sA  * LOG2E;      // p = exp2(scl2*x - m2)
    const float b22  = sB2 * LOG2E;
    const float xmax = sXmax;
    const float xmin = sXmin;

    const f32x4* xs4 = reinterpret_cast<const f32x4*>(xs);
    const bool act31 = (q < 31);         // phase-1: 31 lanes x 8 floats = 248 cols
    f32x4 xlo = {0.f,0.f,0.f,0.f}, xhi = {0.f,0.f,0.f,0.f};
    if (act31) { xlo = xs4[q]; xhi = xs4[31 + q]; }

    float ysum = 0.f;

    // ================= PHASE 1: denominators only (no global stores) =========
    // Each wave handles 2 rows/iter (one per half-wave); 31 iters => 248 rows.
    #pragma unroll 2
    for (int i = 0; i < 31; ++i) {
        const int r = 8 * i + 2 * wave + h;
        const float scl = fmaf(a2, xs[r], b22);
        const float ml  = (scl >= 0.f) ? scl * xmax : scl * xmin;

        float sum = 0.f, xp = 0.f;
        if (act31) {
            f32x4 plo, phi;
            plo.x = __builtin_amdgcn_exp2f(fmaf(scl, xlo.x, -ml));
            plo.y = __builtin_amdgcn_exp2f(fmaf(scl, xlo.y, -ml));
            plo.z = __builtin_amdgcn_exp2f(fmaf(scl, xlo.z, -ml));
            plo.w = __builtin_amdgcn_exp2f(fmaf(scl, xlo.w, -ml));
            phi.x = __builtin_amdgcn_exp2f(fmaf(scl, xhi.x, -ml));
            phi.y = __builtin_amdgcn_exp2f(fmaf(scl, xhi.y, -ml));
            phi.z = __builtin_amdgcn_exp2f(fmaf(scl, xhi.z, -ml));
            phi.w = __builtin_amdgcn_exp2f(fmaf(scl, xhi.w, -ml));
            sum = ((plo.x + plo.y) + (plo.z + plo.w)) + ((phi.x + phi.y) + (phi.z + phi.w));
            xp  = ((plo.x * xlo.x + plo.y * xlo.y) + (plo.z * xlo.z + plo.w * xlo.w))
                + ((phi.x * xhi.x + phi.y * xhi.y) + (phi.z * xhi.z + phi.w * xhi.w));
        }
        #pragma unroll
        for (int off = 16; off > 0; off >>= 1) {
            sum += __shfl_xor(sum, off, 64);
            xp  += __shfl_xor(xp,  off, 64);
        }
        const float inv = __builtin_amdgcn_rcpf(sum);
        ysum += xp * inv;

        if (q == 0) {
            sRow[r][0] = scl;
            sRow[r][1] = -ml;
            sRow[r][2] = inv;
        }
    }

    // out-vector reduction (while params land in LDS)
    if (q == 0) sred[wave * 2 + h] = ysum;
    __syncthreads();
    if (tid == 0) {
        float s = 0.f;
        #pragma unroll
        for (int k = 0; k < 8; ++k) s += sred[k];
        sYbar = s * (1.0f / CC);
    }

    // ================= PHASE 2: pure streaming store, no cross-lane ops ======
    // Wave w writes rows [62w, 62w+62): contiguous 61.5 KB stream per wave.
    // One 992B wave-store per row (62 lanes x 16B).
    const bool act62 = (lane < 62);
    f32x4 xv = {0.f,0.f,0.f,0.f};
    __syncthreads();                     // sRow + sYbar ready
    if (act62) xv = xs4[lane];

    const size_t slice = (size_t)bt * (CC * CC);
    const int rbase = wave * 62;
    float* wbase = wts + slice + (size_t)rbase * CC;

    #pragma unroll 4
    for (int j = 0; j < 62; ++j) {
        const f32x4 prm = *reinterpret_cast<const f32x4*>(sRow[rbase + j]); // broadcast
        f32x4 o;
        o.x = __builtin_amdgcn_exp2f(fmaf(prm.x, xv.x, prm.y)) * prm.z;
        o.y = __builtin_amdgcn_exp2f(fmaf(prm.x, xv.y, prm.y)) * prm.z;
        o.z = __builtin_amdgcn_exp2f(fmaf(prm.x, xv.z, prm.y)) * prm.z;
        o.w = __builtin_amdgcn_exp2f(fmaf(prm.x, xv.w, prm.y)) * prm.z;
        if (act62)
            reinterpret_cast<f32x4*>(wbase + (size_t)j * CC)[lane] = o;
    }

    if (tid < DD)
        out[(size_t)bt * DD + tid] = fmaf(wv[tid], sYbar, bv[tid]);
}

extern "C" void kernel_launch(void* const* d_in, const int* in_sizes, int n_in,
                              void* d_out, int out_size, void* d_ws, size_t ws_size,
                              hipStream_t stream) {
    const float* x  = (const float*)d_in[0];
    const float* wq = (const float*)d_in[1];
    const float* bq = (const float*)d_in[2];
    const float* wk = (const float*)d_in[3];
    const float* bk = (const float*)d_in[4];
    const float* wv = (const float*)d_in[5];
    const float* bv = (const float*)d_in[6];

    float* out = (float*)d_out;                          // [B,T,D]
    float* wts = (float*)d_out + (size_t)BB * TT * DD;   // [B,T,C,C]

    csa_kernel<<<dim3(BB * TT), dim3(256), 0, stream>>>(x, wq, bq, wk, bk, wv, bv, out, wts);
}

// Round 4
// 105.025 us; speedup vs baseline: 1.0747x; 1.0747x over previous
//
#include <hip/hip_runtime.h>
#include <math.h>

#define BB 4
#define CC 248
#define TT 500
#define DD 64
#define NQ (CC * CC / 4)   // 15376 float4 quads per (b,t) tile

typedef float f32x4 __attribute__((ext_vector_type(4)));

__global__ __launch_bounds__(256) void csa_kernel(
    const float* __restrict__ x,
    const float* __restrict__ wq, const float* __restrict__ bq,
    const float* __restrict__ wk, const float* __restrict__ bk,
    const float* __restrict__ wv, const float* __restrict__ bv,
    float* __restrict__ out, float* __restrict__ wts)
{
    const int bt = blockIdx.x;          // 0 .. B*T-1
    const int b  = bt / TT;
    const int t  = bt % TT;
    const int tid  = threadIdx.x;
    const int wave = tid >> 6;
    const int lane = tid & 63;

    __shared__ __align__(16) float xs[CC];
    __shared__ __align__(16) f32x4 sRowV[CC];   // {s2, -m2, inv, 0} per row
    __shared__ float sred[8];
    __shared__ float sA, sB2, sXmax, sXmin, sYbar;

    // ---- load x slice: x[b, c, t] ----
    if (tid < CC) xs[tid] = x[((size_t)b * CC + tid) * TT + t];

    // ---- wave 1: a = wq.wk/8, b2 = bq.wk/8 ----
    if (wave == 1) {
        float wkv = wk[lane];
        float pa = wq[lane] * wkv;
        float pb = bq[lane] * wkv;
        #pragma unroll
        for (int off = 32; off > 0; off >>= 1) {
            pa += __shfl_xor(pa, off, 64);
            pb += __shfl_xor(pb, off, 64);
        }
        if (lane == 0) { sA = pa * 0.125f; sB2 = pb * 0.125f; }
    }
    __syncthreads();

    // ---- block reduce xmax / xmin ----
    float vmax = -INFINITY, vmin = INFINITY;
    if (tid < CC) { vmax = xs[tid]; vmin = vmax; }
    #pragma unroll
    for (int off = 32; off > 0; off >>= 1) {
        vmax = fmaxf(vmax, __shfl_xor(vmax, off, 64));
        vmin = fminf(vmin, __shfl_xor(vmin, off, 64));
    }
    if (lane == 0) { sred[wave] = vmax; sred[4 + wave] = vmin; }
    __syncthreads();
    if (tid == 0) {
        sXmax = fmaxf(fmaxf(sred[0], sred[1]), fmaxf(sred[2], sred[3]));
        sXmin = fminf(fminf(sred[4], sred[5]), fminf(sred[6], sred[7]));
    }
    __syncthreads();

    const float LOG2E = 1.4426950408889634f;
    const float a2   = sA  * LOG2E;      // p = exp2(s2*x_e - m2)
    const float b22  = sB2 * LOG2E;
    const float xmax = sXmax;
    const float xmin = sXmin;
    const f32x4* xs4 = reinterpret_cast<const f32x4*>(xs);

    // ============ PHASE A: thread-per-row params, zero cross-lane ops ========
    const int  r      = tid;
    const bool rowact = (r < CC);
    const float xr = rowact ? xs[r] : 0.f;
    const float s2 = fmaf(a2, xr, b22);
    const float m2 = (s2 >= 0.f) ? s2 * xmax : s2 * xmin;

    float d0 = 0.f, d1 = 0.f, d2 = 0.f, d3 = 0.f;   // denominator accumulators
    float p0 = 0.f, p1 = 0.f, p2 = 0.f, p3 = 0.f;   // x-weighted accumulators
    #pragma unroll 2
    for (int j = 0; j < CC / 4; ++j) {
        const f32x4 xv = xs4[j];                    // broadcast read
        const float e0 = __builtin_amdgcn_exp2f(fmaf(s2, xv.x, -m2));
        const float e1 = __builtin_amdgcn_exp2f(fmaf(s2, xv.y, -m2));
        const float e2 = __builtin_amdgcn_exp2f(fmaf(s2, xv.z, -m2));
        const float e3 = __builtin_amdgcn_exp2f(fmaf(s2, xv.w, -m2));
        d0 += e0; d1 += e1; d2 += e2; d3 += e3;
        p0 = fmaf(e0, xv.x, p0); p1 = fmaf(e1, xv.y, p1);
        p2 = fmaf(e2, xv.z, p2); p3 = fmaf(e3, xv.w, p3);
    }
    const float denom = (d0 + d1) + (d2 + d3);
    const float xp    = (p0 + p1) + (p2 + p3);
    const float inv   = __builtin_amdgcn_rcpf(denom);
    if (rowact) {
        f32x4 prm; prm.x = s2; prm.y = -m2; prm.z = inv; prm.w = 0.f;
        sRowV[r] = prm;
    }

    // ---- ybar = mean_r (xp_r * inv_r): wave reduce then block combine ----
    float yr = rowact ? xp * inv : 0.f;
    #pragma unroll
    for (int off = 32; off > 0; off >>= 1) yr += __shfl_xor(yr, off, 64);
    if (lane == 0) sred[wave] = yr;
    __syncthreads();
    if (tid == 0)
        sYbar = (sred[0] + sred[1] + sred[2] + sred[3]) * (1.0f / CC);
    __syncthreads();   // sRowV + sYbar ready

    // ============ PHASE B: fill-shaped streaming stores =======================
    // Flat quad index over the 248x248 tile: every wave-store is 64 lanes x 16B
    // = 1024B contiguous & aligned, exactly like fillBufferAligned.
    f32x4* wq4 = reinterpret_cast<f32x4*>(wts + (size_t)bt * (CC * CC));

    #pragma unroll 2
    for (int it = 0; it < NQ / 256; ++it) {         // 60 full iterations
        const int idx = it * 256 + tid;
        const int row = idx / 62;                   // magic-mul
        const int c4  = idx - row * 62;
        const f32x4 prm = sRowV[row];               // <=2 distinct rows: broadcast
        const f32x4 xv  = xs4[c4];
        f32x4 o;
        o.x = __builtin_amdgcn_exp2f(fmaf(prm.x, xv.x, prm.y)) * prm.z;
        o.y = __builtin_amdgcn_exp2f(fmaf(prm.x, xv.y, prm.y)) * prm.z;
        o.z = __builtin_amdgcn_exp2f(fmaf(prm.x, xv.z, prm.y)) * prm.z;
        o.w = __builtin_amdgcn_exp2f(fmaf(prm.x, xv.w, prm.y)) * prm.z;
        wq4[idx] = o;
    }
    {   // tail: 15376 - 60*256 = 16 quads
        const int idx = (NQ / 256) * 256 + tid;
        if (tid < NQ - (NQ / 256) * 256) {
            const int row = idx / 62;
            const int c4  = idx - row * 62;
            const f32x4 prm = sRowV[row];
            const f32x4 xv  = xs4[c4];
            f32x4 o;
            o.x = __builtin_amdgcn_exp2f(fmaf(prm.x, xv.x, prm.y)) * prm.z;
            o.y = __builtin_amdgcn_exp2f(fmaf(prm.x, xv.y, prm.y)) * prm.z;
            o.z = __builtin_amdgcn_exp2f(fmaf(prm.x, xv.z, prm.y)) * prm.z;
            o.w = __builtin_amdgcn_exp2f(fmaf(prm.x, xv.w, prm.y)) * prm.z;
            wq4[idx] = o;
        }
    }

    if (tid < DD)
        out[(size_t)bt * DD + tid] = fmaf(wv[tid], sYbar, bv[tid]);
}

extern "C" void kernel_launch(void* const* d_in, const int* in_sizes, int n_in,
                              void* d_out, int out_size, void* d_ws, size_t ws_size,
                              hipStream_t stream) {
    const float* x  = (const float*)d_in[0];
    const float* wq = (const float*)d_in[1];
    const float* bq = (const float*)d_in[2];
    const float* wk = (const float*)d_in[3];
    const float* bk = (const float*)d_in[4];
    const float* wv = (const float*)d_in[5];
    const float* bv = (const float*)d_in[6];

    float* out = (float*)d_out;                          // [B,T,D]
    float* wts = (float*)d_out + (size_t)BB * TT * DD;   // [B,T,C,C]

    csa_kernel<<<dim3(BB * TT), dim3(256), 0, stream>>>(x, wq, bq, wk, bk, wv, bv, out, wts);
}